// Round 20
// baseline (132.673 us; speedup 1.0000x reference)
//
#include <hip/hip_runtime.h>
#include <hip/hip_bf16.h>

typedef __attribute__((ext_vector_type(4))) float f32x4;
typedef __attribute__((ext_vector_type(4))) uint u32x4;
typedef __attribute__((ext_vector_type(8))) short bf16x8;

#define M_TOTAL 32768
#define N_TOTAL 1024
#define K_TOTAL 1024

__device__ __forceinline__ uint pk2(float a, float b) {
  __hip_bfloat162 h = __float22bfloat162_rn(make_float2(a, b));  // v_cvt_pk_bf16_f32
  uint u;
  __builtin_memcpy(&u, &h, 4);
  return u;
}

// Non-draining barrier (fallback kernels only).
#define SOFT_BARRIER() do {                                                   \
    __builtin_amdgcn_sched_barrier(0);                                        \
    asm volatile("s_waitcnt lgkmcnt(0)" ::: "memory");                        \
    __builtin_amdgcn_s_barrier();                                             \
    __builtin_amdgcn_sched_barrier(0);                                        \
  } while (0)

// Counted-vmcnt barriers (gemm9): wait only the OLDEST slab's 6 vmem ops
// (2 gload_lds + 4 B-loads); the next slab's 6 stay in flight (T4/m218).
#define WAIT6_BAR() do {                                                      \
    __builtin_amdgcn_sched_barrier(0);                                        \
    asm volatile("s_waitcnt vmcnt(6)" ::: "memory");                          \
    __builtin_amdgcn_s_barrier();                                             \
    __builtin_amdgcn_sched_barrier(0);                                        \
  } while (0)
#define WAIT0_BAR() do {                                                      \
    __builtin_amdgcn_sched_barrier(0);                                        \
    asm volatile("s_waitcnt vmcnt(0)" ::: "memory");                          \
    __builtin_amdgcn_s_barrier();                                             \
    __builtin_amdgcn_sched_barrier(0);                                        \
  } while (0)

// ===========================================================================
// Pass 1a: X (32768x1024 f32) -> fragment-major bf16 in wsx (64 MB).
// Frag (fm, kb): 1 KB contiguous; lane l holds
// X[fm*16 + (l&15)][kb*32 + (l>>4)*8 .. +7]. Verified rounds 10-19.
// ===========================================================================
__global__ __launch_bounds__(256) void conv_x(
    const float* __restrict__ X, ushort* __restrict__ wsx)
{
  const int g = blockIdx.x * 256 + (int)threadIdx.x;
  const int wid = g >> 6;   // (fm 0..2047, kb 0..31)
  const int lane = g & 63;
  const int fm = wid >> 5;
  const int kb = wid & 31;
  const float* p = X + (size_t)(fm * 16 + (lane & 15)) * K_TOTAL
                     + kb * 32 + (lane >> 4) * 8;
  f32x4 lo = *(const f32x4*)p;
  f32x4 hi = *(const f32x4*)(p + 4);
  u32x4 v;
  v[0] = pk2(lo[0], lo[1]); v[1] = pk2(lo[2], lo[3]);
  v[2] = pk2(hi[0], hi[1]); v[3] = pk2(hi[2], hi[3]);
  *(u32x4*)(wsx + (size_t)wid * 512 + lane * 8) = v;
}

// ===========================================================================
// Pass 1b: 4x 256x256 f32 S-matrices -> fragment-major bf16 (512 KB).
// Verified rounds 7-19 (absmax 0.03125).
// ===========================================================================
__global__ __launch_bounds__(256) void conv_b(
    const float* __restrict__ Rm, const float* __restrict__ Im,
    const float* __restrict__ Jm, const float* __restrict__ Km,
    ushort* __restrict__ ws)
{
  const int slot = blockIdx.x * 256 + (int)threadIdx.x;  // 0..32767
  const int lane = slot & 63;
  const int kb = (slot >> 6) & 7;
  const int cb = (slot >> 9) & 15;
  const int si = slot >> 13;
  const float* S = (si == 0) ? Rm : (si == 1) ? Im : (si == 2) ? Jm : Km;
  const float* p = S + (cb * 16 + (lane & 15)) * 256 + kb * 32 + (lane >> 4) * 8;
  f32x4 lo = *(const f32x4*)p;
  f32x4 hi = *(const f32x4*)(p + 4);
  u32x4 v;
  v[0] = pk2(lo[0], lo[1]); v[1] = pk2(lo[2], lo[3]);
  v[2] = pk2(hi[0], hi[1]); v[3] = pk2(hi[2], hi[3]);
  *(u32x4*)(ws + (size_t)slot * 8) = v;
}

// ===========================================================================
// Pass 2 (gemm9p = r14/r19 champion + T5 setprio around the MFMA cluster):
// block 128x128, 4 waves 2x2 (wave 64x64, acc=64 AGPR). K-slab=32.
// A: global_load_lds frag-major wsx -> TRIPLE-buffered shared LDS (24 KB).
// B: frag-direct from L2-resident wsb, triple-buffered regs (48 VGPR max).
// Counted vmcnt(6) + barrier per slab (T4, never drains in-loop).
// T5 rationale: within-block waves are lockstep (m190-null), but 3 blocks/CU
// run at skewed phases -> setprio arbitrates MFMA-entering waves over the
// other blocks' staging waves (m191 regime, +4-7% there). Zero reg change.
// ===========================================================================
#define STAGE9(s, lb) do {                                                    \
    _Pragma("unroll")                                                         \
    for (int j = 0; j < 2; ++j) {                                             \
      const int f_ = (wv << 1) + j;                                           \
      const ushort* s_ = WSX + ((size_t)(fmB + f_) * 32 + (s)) * 512          \
                         + lane * 8;                                          \
      __builtin_amdgcn_global_load_lds((const uint*)s_,                       \
                                       (uint*)((lb) + f_ * 512), 16, 0, 0);   \
    }                                                                         \
  } while (0)

#define LOADB9(s, BF) do {                                                    \
    const int si_ = a_idx ^ ((s) >> 3);                                       \
    const int kbq_ = (s) & 7;                                                 \
    _Pragma("unroll")                                                         \
    for (int ni = 0; ni < 4; ++ni)                                            \
      BF[ni] = *(const bf16x8*)(                                              \
          WSB + ((size_t)((si_ * 16 + cb0 + ni) * 8 + kbq_)) * 512            \
          + lane * 8);                                                        \
  } while (0)

#define SGN9(s, BF) do {                                                      \
    if ((0x284Eu >> ((a_idx << 2) | ((s) >> 3))) & 1u) {                      \
      _Pragma("unroll")                                                       \
      for (int f = 0; f < 4; ++f) {                                           \
        u32x4 u_ = __builtin_bit_cast(u32x4, BF[f]);                          \
        u_[0] ^= 0x80008000u; u_[1] ^= 0x80008000u;                           \
        u_[2] ^= 0x80008000u; u_[3] ^= 0x80008000u;                           \
        BF[f] = __builtin_bit_cast(bf16x8, u_);                               \
      }                                                                       \
    }                                                                         \
  } while (0)

#define COMPUTE9(lb, BF) do {                                                 \
    __builtin_amdgcn_s_setprio(1);                                            \
    _Pragma("unroll")                                                         \
    for (int mi = 0; mi < 4; ++mi) {                                          \
      bf16x8 af_ = *(const bf16x8*)((lb) + (frW + mi) * 512 + lane * 8);      \
      _Pragma("unroll")                                                       \
      for (int ni = 0; ni < 4; ++ni)                                          \
        acc[mi][ni] = __builtin_amdgcn_mfma_f32_16x16x32_bf16(                \
            af_, BF[ni], acc[mi][ni], 0, 0, 0);                               \
    }                                                                         \
    __builtin_amdgcn_s_setprio(0);                                            \
  } while (0)

__global__ __launch_bounds__(256, 3) void qlin_gemm9p(
    const ushort* __restrict__ WSX, const ushort* __restrict__ WSB,
    const float* __restrict__ bias, float* __restrict__ Y)
{
  // 2048 blocks = 256 m x 8 n; XCD-bijective swizzle (2048%8==0), n fastest.
  const int per = 2048 >> 3;  // 256
  const int bid = (int)blockIdx.x;
  const int swz = (bid & 7) * per + (bid >> 3);
  const int mblk = swz >> 3;       // 0..255
  const int nblk = swz & 7;        // 0..7
  const int m0 = mblk << 7;
  const int n0 = nblk << 7;
  const int a_idx = nblk >> 1;     // 256-col source quadrant

  const int tid = (int)threadIdx.x;
  const int lane = tid & 63;
  const int wv = tid >> 6;         // 0..3
  const int wr = wv >> 1;          // wave row 0/1
  const int wc = wv & 1;           // wave col 0/1
  const int fmB = mblk << 3;       // block's global row-frag base (8 frags)
  const int frW = wr << 2;         // wave's local row-frag base (0/4)
  const int cb0 = ((nblk & 1) << 3) + (wc << 2);  // B col-frag base

  __shared__ __align__(16) ushort smA[3 * 8 * 512];  // 3 bufs x 8 frags x 1KB
  ushort* const lbuf0 = smA;
  ushort* const lbuf1 = smA + 8 * 512;
  ushort* const lbuf2 = smA + 16 * 512;

  bf16x8 bq0[4], bq1[4], bq2[4];
  f32x4 acc[4][4];
#pragma unroll
  for (int i = 0; i < 4; ++i)
#pragma unroll
    for (int j = 0; j < 4; ++j) acc[i][j] = (f32x4)(0.0f);

  // prologue: slabs 0,1 in flight (12 vmem outstanding)
  STAGE9(0, lbuf0); LOADB9(0, bq0);
  STAGE9(1, lbuf1); LOADB9(1, bq1);

  // steady state: 10 iterations x 3 slabs; wait vmcnt(6) per slab.
#pragma unroll 1
  for (int s = 0; s < 30; s += 3) {
    WAIT6_BAR();                                 // slab s landed
    STAGE9(s + 2, lbuf2); LOADB9(s + 2, bq2);    // buf2 last read at slab s-1
    SGN9(s, bq0); COMPUTE9(lbuf0, bq0);
    WAIT6_BAR();
    STAGE9(s + 3, lbuf0); LOADB9(s + 3, bq0);
    SGN9(s + 1, bq1); COMPUTE9(lbuf1, bq1);
    WAIT6_BAR();
    STAGE9(s + 4, lbuf1); LOADB9(s + 4, bq1);
    SGN9(s + 2, bq2); COMPUTE9(lbuf2, bq2);
  }
  // tail: slab 30 (buf0/bq0), slab 31 (buf1/bq1)
  WAIT6_BAR();
  SGN9(30, bq0); COMPUTE9(lbuf0, bq0);
  WAIT0_BAR();
  SGN9(31, bq1); COMPUTE9(lbuf1, bq1);

  // epilogue: C/D layout col = lane&15, row = (lane>>4)*4 + reg  [m89-verified]
#pragma unroll
  for (int ni = 0; ni < 4; ++ni) {
    const int col = n0 + (wc << 6) + (ni << 4) + (lane & 15);
    const float bv = bias[col];
#pragma unroll
    for (int mi = 0; mi < 4; ++mi) {
      const int r0e = m0 + (wr << 6) + (mi << 4) + ((lane >> 4) << 2);
#pragma unroll
      for (int j = 0; j < 4; ++j)
        Y[(size_t)(r0e + j) * N_TOTAL + col] = acc[mi][ni][j] + bv;
    }
  }
}

// ===========================================================================
// Mid-tier (round-7 champion structure): 256x256 tile, B frag-direct, A LDS.
// ===========================================================================
#define BM2 256
#define BN2 256
#define BK2 64
#define NT2 512
#define NSTEPS2 (K_TOTAL / BK2)

#define LOAD_A2(kk) do {                                                      \
    _Pragma("unroll")                                                         \
    for (int cc = 0; cc < 4; ++cc) {                                          \
      const float* pa_ = X + (size_t)(m0 + r0 + 64 * cc) * K_TOTAL + (kk) + k0;\
      rA[2 * cc]     = *(const f32x4*)pa_;                                    \
      rA[2 * cc + 1] = *(const f32x4*)(pa_ + 4);                              \
    }                                                                         \
  } while (0)

#define COMMIT_A2(dst) do {                                                   \
    _Pragma("unroll")                                                         \
    for (int cc = 0; cc < 4; ++cc) {                                          \
      u32x4 va_;                                                              \
      va_[0] = pk2(rA[2 * cc][0], rA[2 * cc][1]);                             \
      va_[1] = pk2(rA[2 * cc][2], rA[2 * cc][3]);                             \
      va_[2] = pk2(rA[2 * cc + 1][0], rA[2 * cc + 1][1]);                     \
      va_[3] = pk2(rA[2 * cc + 1][2], rA[2 * cc + 1][3]);                     \
      *(u32x4*)((dst) + sbase + 8192 * cc) = va_;                             \
    }                                                                         \
  } while (0)

#define LOAD_B2(kk) do {                                                      \
    const int bsel_ = (kk) >> 8;                                              \
    const int si_ = a_idx ^ bsel_;                                            \
    const int kbq_ = ((kk) & 255) >> 5;                                       \
    const ushort* fb_ = WS + ((size_t)((si_ * 16 + wc4) * 8 + kbq_)) * 512    \
                        + lane * 8;                                           \
    _Pragma("unroll")                                                         \
    for (int ks = 0; ks < 2; ++ks)                                            \
      _Pragma("unroll")                                                       \
      for (int ni = 0; ni < 4; ++ni)                                          \
        bq[ks * 4 + ni] = *(const bf16x8*)(fb_ + (ni * 8 + ks) * 512);        \
    if ((0x284Eu >> ((a_idx << 2) | bsel_)) & 1u) {                           \
      _Pragma("unroll")                                                       \
      for (int f = 0; f < 8; ++f) {                                           \
        u32x4 u_ = __builtin_bit_cast(u32x4, bq[f]);                          \
        u_[0] ^= 0x80008000u; u_[1] ^= 0x80008000u;                           \
        u_[2] ^= 0x80008000u; u_[3] ^= 0x80008000u;                           \
        bq[f] = __builtin_bit_cast(bf16x8, u_);                               \
      }                                                                       \
    }                                                                         \
  } while (0)

#define COMPUTE2(src) do {                                                    \
    _Pragma("unroll")                                                         \
    for (int ks = 0; ks < 2; ++ks) {                                          \
      _Pragma("unroll")                                                       \
      for (int mi = 0; mi < 8; ++mi) {                                        \
        const int row_ = frow_a0 + (mi << 4);                                 \
        const int kb_ = (ks << 6) + fkb;                                      \
        bf16x8 af_ = *(const bf16x8*)((src) + row_ * (BK2 * 2)                \
                                      + (kb_ ^ ((row_ & 7) << 4)));           \
        _Pragma("unroll")                                                     \
        for (int ni = 0; ni < 4; ++ni)                                        \
          acc[mi][ni] = __builtin_amdgcn_mfma_f32_16x16x32_bf16(              \
              af_, bq[ks * 4 + ni], acc[mi][ni], 0, 0, 0);                    \
      }                                                                       \
    }                                                                         \
  } while (0)

__global__ __launch_bounds__(NT2, 2) void qlin_gemm2(
    const float* __restrict__ X, const ushort* __restrict__ WS,
    const float* __restrict__ bias, float* __restrict__ Y)
{
  const int per = ((M_TOTAL / BM2) * (N_TOTAL / BN2)) >> 3;  // 64
  const int bid = (int)blockIdx.x;
  const int swz = (bid & 7) * per + (bid >> 3);
  const int m0 = (swz >> 2) * BM2;
  const int nblk = swz & 3;
  const int n0 = nblk * BN2;
  const int a_idx = nblk;

  const int tid = (int)threadIdx.x;
  const int lane = tid & 63;
  const int wave = tid >> 6;
  const int wm = (wave >> 2) << 7;
  const int wc4 = (wave & 3) << 2;

  __shared__ __align__(16) ushort smA[2 * BM2 * BK2];  // 64 KB dbuf
  char* const cS = (char*)smA;

  const int r0 = tid >> 3;
  const int k0 = (tid & 7) << 3;
  const int sbase = r0 * (BK2 * 2) + ((k0 * 2) ^ ((r0 & 7) << 4));

  f32x4 rA[8];
  bf16x8 bq[8];
  f32x4 acc[8][4];
#pragma unroll
  for (int i = 0; i < 8; ++i)
#pragma unroll
    for (int j = 0; j < 4; ++j) acc[i][j] = (f32x4)(0.0f);

  const int frow_a0 = wm + (lane & 15);
  const int fkb = (lane >> 4) << 4;

  LOAD_A2(0);
  COMMIT_A2(cS);
  LOAD_A2(BK2);
  SOFT_BARRIER();

#pragma unroll 1
  for (int k = 0; k < NSTEPS2; ++k) {
    char* const rbuf = cS + ((k & 1) << 15);
    char* const wbuf = cS + (((k + 1) & 1) << 15);
    COMMIT_A2(wbuf);
    LOAD_B2(k * BK2);
    if (k + 2 < NSTEPS2) LOAD_A2((k + 2) * BK2);
    COMPUTE2(rbuf);
    SOFT_BARRIER();
  }

#pragma unroll
  for (int ni = 0; ni < 4; ++ni) {
    const int col = n0 + (wc4 << 4) + (ni << 4) + (lane & 15);
    const float bv = bias[col];
#pragma unroll
    for (int mi = 0; mi < 8; ++mi) {
      const int r0e = m0 + wm + (mi << 4) + ((lane >> 4) << 2);
#pragma unroll
      for (int j = 0; j < 4; ++j)
        Y[(size_t)(r0e + j) * N_TOTAL + col] = acc[mi][ni][j] + bv;
    }
  }
}

// ===========================================================================
// No-ws fallback (round-6, 126 us).
// ===========================================================================
#define BM 128
#define BN 128
#define BK 64
#define NTHREADS 256
#define NSTEPS (K_TOTAL / BK)

#define LOAD_TILE(kk) do {                                                    \
    const int si_ = a_idx ^ ((kk) >> 8);                                      \
    const float* Bsrc_ = (si_ == 0) ? Rm : (si_ == 1) ? Im                    \
                       : (si_ == 2) ? Jm : Km;                                \
    const int kloc_ = (kk) & 255;                                             \
    _Pragma("unroll")                                                         \
    for (int cc = 0; cc < 4; ++cc) {                                          \
      const float* pa_ = X + (size_t)(m0 + r0 + 32 * cc) * K_TOTAL + (kk) + k0;\
      rA[2 * cc]     = *(const f32x4*)pa_;                                    \
      rA[2 * cc + 1] = *(const f32x4*)(pa_ + 4);                              \
      const float* pb_ = Bsrc_ + (o_src + r0 + 32 * cc) * 256 + kloc_ + k0;   \
      rB[2 * cc]     = *(const f32x4*)pb_;                                    \
      rB[2 * cc + 1] = *(const f32x4*)(pb_ + 4);                              \
    }                                                                         \
  } while (0)

#define COMMIT_TILE(kk, dst) do {                                             \
    const uint neg_ = (0x284Eu >> ((a_idx << 2) | ((kk) >> 8))) & 1u;         \
    _Pragma("unroll")                                                         \
    for (int cc = 0; cc < 4; ++cc) {                                          \
      u32x4 va_;                                                              \
      va_[0] = pk2(rA[2 * cc][0], rA[2 * cc][1]);                             \
      va_[1] = pk2(rA[2 * cc][2], rA[2 * cc][3]);                             \
      va_[2] = pk2(rA[2 * cc + 1][0], rA[2 * cc + 1][1]);                     \
      va_[3] = pk2(rA[2 * cc + 1][2], rA[2 * cc + 1][3]);                     \
      *(u32x4*)((dst) + sbase + 4096 * cc) = va_;                             \
    }                                                                         \
    if (neg_) {                                                               \
      _Pragma("unroll")                                                       \
      for (int cc = 0; cc < 4; ++cc) {                                        \
        u32x4 vb_;                                                            \
        vb_[0] = pk2(-rB[2 * cc][0], -rB[2 * cc][1]);                         \
        vb_[1] = pk2(-rB[2 * cc][2], -rB[2 * cc][3]);                         \
        vb_[2] = pk2(-rB[2 * cc + 1][0], -rB[2 * cc + 1][1]);                 \
        vb_[3] = pk2(-rB[2 * cc + 1][2], -rB[2 * cc + 1][3]);                 \
        *(u32x4*)((dst) + 16384 + sbase + 4096 * cc) = vb_;                   \
      }                                                                       \
    } else {                                                                  \
      _Pragma("unroll")                                                       \
      for (int cc = 0; cc < 4; ++cc) {                                        \
        u32x4 vb_;                                                            \
        vb_[0] = pk2(rB[2 * cc][0], rB[2 * cc][1]);                           \
        vb_[1] = pk2(rB[2 * cc][2], rB[2 * cc][3]);                           \
        vb_[2] = pk2(rB[2 * cc + 1][0], rB[2 * cc + 1][1]);                   \
        vb_[3] = pk2(rB[2 * cc + 1][2], rB[2 * cc + 1][3]);                   \
        *(u32x4*)((dst) + 16384 + sbase + 4096 * cc) = vb_;                   \
      }                                                                       \
    }                                                                         \
  } while (0)

#define COMPUTE_TILE(src) do {                                                \
    _Pragma("unroll")                                                         \
    for (int ks = 0; ks < 2; ++ks) {                                          \
      const int kb_ = (ks << 6) + fkb;                                        \
      bf16x8 af_[4], bf_[4];                                                  \
      _Pragma("unroll")                                                       \
      for (int mi = 0; mi < 4; ++mi) {                                        \
        const int row_ = frow_a0 + (mi << 4);                                 \
        af_[mi] = *(const bf16x8*)((src) + row_ * (BK * 2)                    \
                                   + (kb_ ^ ((row_ & 7) << 4)));              \
      }                                                                       \
      _Pragma("unroll")                                                       \
      for (int ni = 0; ni < 4; ++ni) {                                        \
        const int row_ = frow_b0 + (ni << 4);                                 \
        bf_[ni] = *(const bf16x8*)((src) + 16384 + row_ * (BK * 2)            \
                                   + (kb_ ^ ((row_ & 7) << 4)));              \
      }                                                                       \
      _Pragma("unroll")                                                       \
      for (int mi = 0; mi < 4; ++mi)                                          \
        _Pragma("unroll")                                                     \
        for (int ni = 0; ni < 4; ++ni)                                        \
          acc[mi][ni] = __builtin_amdgcn_mfma_f32_16x16x32_bf16(              \
              af_[mi], bf_[ni], acc[mi][ni], 0, 0, 0);                        \
    }                                                                         \
  } while (0)

__global__ __launch_bounds__(NTHREADS, 2) void qlin_gemm(
    const float* __restrict__ X, const float* __restrict__ Rm,
    const float* __restrict__ Im, const float* __restrict__ Jm,
    const float* __restrict__ Km, const float* __restrict__ bias,
    float* __restrict__ Y)
{
  const int per = ((M_TOTAL / BM) * (N_TOTAL / BN)) >> 3;
  const int bid = (int)blockIdx.x;
  const int swz = (bid & 7) * per + (bid >> 3);
  const int m0 = (swz >> 3) * BM;
  const int n0 = (swz & 7) * BN;

  const int tid = (int)threadIdx.x;
  const int lane = tid & 63;
  const int wave = tid >> 6;
  const int wm = (wave >> 1) << 6;
  const int wn = (wave & 1) << 6;

  __shared__ __align__(16) ushort sm[2 * 2 * BM * BK];
  char* const cS = (char*)sm;

  const int a_idx = n0 >> 8;
  const int o_src = n0 & 255;

  const int r0 = tid >> 3;
  const int k0 = (tid & 7) << 3;
  const int sbase = r0 * (BK * 2) + ((k0 * 2) ^ ((r0 & 7) << 4));

  f32x4 rA[8], rB[8];
  f32x4 acc[4][4];
#pragma unroll
  for (int i = 0; i < 4; ++i)
#pragma unroll
    for (int j = 0; j < 4; ++j) acc[i][j] = (f32x4)(0.0f);

  const int frow_a0 = wm + (lane & 15);
  const int frow_b0 = wn + (lane & 15);
  const int fkb = (lane >> 4) << 4;

  LOAD_TILE(0);
  COMMIT_TILE(0, cS);
  LOAD_TILE(BK);
  SOFT_BARRIER();

#pragma unroll 1
  for (int k = 0; k < NSTEPS; ++k) {
    char* const rbuf = cS + ((k & 1) << 15);
    char* const wbuf = cS + (((k + 1) & 1) << 15);
    if (k + 1 < NSTEPS) COMMIT_TILE((k + 1) * BK, wbuf);
    if (k + 2 < NSTEPS) LOAD_TILE((k + 2) * BK);
    COMPUTE_TILE(rbuf);
    SOFT_BARRIER();
  }

#pragma unroll
  for (int ni = 0; ni < 4; ++ni) {
    const int col = n0 + wn + (ni << 4) + (lane & 15);
    const float bv = bias[col];
#pragma unroll
    for (int mi = 0; mi < 4; ++mi) {
      const int r0e = m0 + wm + (mi << 4) + ((lane >> 4) << 2);
#pragma unroll
      for (int j = 0; j < 4; ++j)
        Y[(size_t)(r0e + j) * N_TOTAL + col] = acc[mi][ni][j] + bv;
    }
  }
}

extern "C" void kernel_launch(void* const* d_in, const int* in_sizes, int n_in,
                              void* d_out, int out_size, void* d_ws, size_t ws_size,
                              hipStream_t stream) {
  const float* X = (const float*)d_in[0];
  const float* Rm = (const float*)d_in[1];
  const float* Im = (const float*)d_in[2];
  const float* Jm = (const float*)d_in[3];
  const float* Km = (const float*)d_in[4];
  const float* bias = (const float*)d_in[5];
  float* Y = (float*)d_out;

  const size_t needB = (size_t)4 * 256 * 256 * 2;            // 512 KB
  const size_t needX = (size_t)M_TOTAL * K_TOTAL * 2;        // 64 MB

  if (ws_size >= needX + needB) {
    ushort* wsx = (ushort*)d_ws;
    ushort* wsb = wsx + (size_t)M_TOTAL * K_TOTAL;
    conv_x<<<dim3(16384), dim3(256), 0, stream>>>(X, wsx);
    conv_b<<<dim3(128), dim3(256), 0, stream>>>(Rm, Im, Jm, Km, wsb);
    qlin_gemm9p<<<dim3(2048), dim3(256), 0, stream>>>(wsx, wsb, bias, Y);
  } else if (ws_size >= needB) {
    ushort* wsb = (ushort*)d_ws;
    conv_b<<<dim3(128), dim3(256), 0, stream>>>(Rm, Im, Jm, Km, wsb);
    qlin_gemm2<<<dim3((M_TOTAL / BM2) * (N_TOTAL / BN2)), dim3(NT2), 0, stream>>>(
        X, wsb, bias, Y);
  } else {
    qlin_gemm<<<dim3((M_TOTAL / BM) * (N_TOTAL / BN)), dim3(NTHREADS), 0, stream>>>(
        X, Rm, Im, Jm, Km, bias, Y);
  }
}

// Round 21
// 116.596 us; speedup vs baseline: 1.1379x; 1.1379x over previous
//
#include <hip/hip_runtime.h>
#include <hip/hip_bf16.h>

typedef __attribute__((ext_vector_type(4))) float f32x4;
typedef __attribute__((ext_vector_type(4))) uint u32x4;
typedef __attribute__((ext_vector_type(8))) short bf16x8;

#define M_TOTAL 32768
#define N_TOTAL 1024
#define K_TOTAL 1024

__device__ __forceinline__ uint pk2(float a, float b) {
  __hip_bfloat162 h = __float22bfloat162_rn(make_float2(a, b));  // v_cvt_pk_bf16_f32
  uint u;
  __builtin_memcpy(&u, &h, 4);
  return u;
}

// Non-draining barrier (fallback kernels only).
#define SOFT_BARRIER() do {                                                   \
    __builtin_amdgcn_sched_barrier(0);                                        \
    asm volatile("s_waitcnt lgkmcnt(0)" ::: "memory");                        \
    __builtin_amdgcn_s_barrier();                                             \
    __builtin_amdgcn_sched_barrier(0);                                        \
  } while (0)

// Counted-vmcnt barriers (gemm9): wait only the OLDEST slab's 6 vmem ops
// (2 gload_lds + 4 B-loads); the next slab's 6 stay in flight (T4/m218).
#define WAIT6_BAR() do {                                                      \
    __builtin_amdgcn_sched_barrier(0);                                        \
    asm volatile("s_waitcnt vmcnt(6)" ::: "memory");                          \
    __builtin_amdgcn_s_barrier();                                             \
    __builtin_amdgcn_sched_barrier(0);                                        \
  } while (0)
#define WAIT0_BAR() do {                                                      \
    __builtin_amdgcn_sched_barrier(0);                                        \
    asm volatile("s_waitcnt vmcnt(0)" ::: "memory");                          \
    __builtin_amdgcn_s_barrier();                                             \
    __builtin_amdgcn_sched_barrier(0);                                        \
  } while (0)

// ===========================================================================
// Pass 1a: X (32768x1024 f32) -> fragment-major bf16 in wsx (64 MB).
// Frag (fm, kb): 1 KB contiguous; lane l holds
// X[fm*16 + (l&15)][kb*32 + (l>>4)*8 .. +7]. Verified rounds 10-20.
// ===========================================================================
__global__ __launch_bounds__(256) void conv_x(
    const float* __restrict__ X, ushort* __restrict__ wsx)
{
  const int g = blockIdx.x * 256 + (int)threadIdx.x;
  const int wid = g >> 6;   // (fm 0..2047, kb 0..31)
  const int lane = g & 63;
  const int fm = wid >> 5;
  const int kb = wid & 31;
  const float* p = X + (size_t)(fm * 16 + (lane & 15)) * K_TOTAL
                     + kb * 32 + (lane >> 4) * 8;
  f32x4 lo = *(const f32x4*)p;
  f32x4 hi = *(const f32x4*)(p + 4);
  u32x4 v;
  v[0] = pk2(lo[0], lo[1]); v[1] = pk2(lo[2], lo[3]);
  v[2] = pk2(hi[0], hi[1]); v[3] = pk2(hi[2], hi[3]);
  *(u32x4*)(wsx + (size_t)wid * 512 + lane * 8) = v;
}

// ===========================================================================
// Pass 1b: 4x 256x256 f32 S-matrices -> fragment-major bf16 (512 KB).
// Verified rounds 7-20 (absmax 0.03125).
// ===========================================================================
__global__ __launch_bounds__(256) void conv_b(
    const float* __restrict__ Rm, const float* __restrict__ Im,
    const float* __restrict__ Jm, const float* __restrict__ Km,
    ushort* __restrict__ ws)
{
  const int slot = blockIdx.x * 256 + (int)threadIdx.x;  // 0..32767
  const int lane = slot & 63;
  const int kb = (slot >> 6) & 7;
  const int cb = (slot >> 9) & 15;
  const int si = slot >> 13;
  const float* S = (si == 0) ? Rm : (si == 1) ? Im : (si == 2) ? Jm : Km;
  const float* p = S + (cb * 16 + (lane & 15)) * 256 + kb * 32 + (lane >> 4) * 8;
  f32x4 lo = *(const f32x4*)p;
  f32x4 hi = *(const f32x4*)(p + 4);
  u32x4 v;
  v[0] = pk2(lo[0], lo[1]); v[1] = pk2(lo[2], lo[3]);
  v[2] = pk2(hi[0], hi[1]); v[3] = pk2(hi[2], hi[3]);
  *(u32x4*)(ws + (size_t)slot * 8) = v;
}

// ===========================================================================
// Pass 2 (gemm9 — CHAMPION, r14/r19: 88-90 us, MfmaUtil 33%, no spill;
// r20 proved setprio REGRESSES this kernel (119 us + 21 MB spill) — omitted):
// block 128x128, 4 waves 2x2 (wave 64x64, acc=64 AGPR). K-slab=32.
// A: global_load_lds frag-major wsx -> TRIPLE-buffered shared LDS (24 KB),
//    2 gload_lds/wave/slab (zero VGPR transit). B: frag-direct from
//    L2-resident wsb, triple-buffered regs (48 VGPR — register-feasible max;
//    64 VGPR spills, r17/r18). Sign via bf16 sign-bit XOR.
// Counted vmcnt(6) + barrier per slab — never drains in-loop (T4/m218).
// ===========================================================================
#define STAGE9(s, lb) do {                                                    \
    _Pragma("unroll")                                                         \
    for (int j = 0; j < 2; ++j) {                                             \
      const int f_ = (wv << 1) + j;                                           \
      const ushort* s_ = WSX + ((size_t)(fmB + f_) * 32 + (s)) * 512          \
                         + lane * 8;                                          \
      __builtin_amdgcn_global_load_lds((const uint*)s_,                       \
                                       (uint*)((lb) + f_ * 512), 16, 0, 0);   \
    }                                                                         \
  } while (0)

#define LOADB9(s, BF) do {                                                    \
    const int si_ = a_idx ^ ((s) >> 3);                                       \
    const int kbq_ = (s) & 7;                                                 \
    _Pragma("unroll")                                                         \
    for (int ni = 0; ni < 4; ++ni)                                            \
      BF[ni] = *(const bf16x8*)(                                              \
          WSB + ((size_t)((si_ * 16 + cb0 + ni) * 8 + kbq_)) * 512            \
          + lane * 8);                                                        \
  } while (0)

#define SGN9(s, BF) do {                                                      \
    if ((0x284Eu >> ((a_idx << 2) | ((s) >> 3))) & 1u) {                      \
      _Pragma("unroll")                                                       \
      for (int f = 0; f < 4; ++f) {                                           \
        u32x4 u_ = __builtin_bit_cast(u32x4, BF[f]);                          \
        u_[0] ^= 0x80008000u; u_[1] ^= 0x80008000u;                           \
        u_[2] ^= 0x80008000u; u_[3] ^= 0x80008000u;                           \
        BF[f] = __builtin_bit_cast(bf16x8, u_);                               \
      }                                                                       \
    }                                                                         \
  } while (0)

#define COMPUTE9(lb, BF) do {                                                 \
    _Pragma("unroll")                                                         \
    for (int mi = 0; mi < 4; ++mi) {                                          \
      bf16x8 af_ = *(const bf16x8*)((lb) + (frW + mi) * 512 + lane * 8);      \
      _Pragma("unroll")                                                       \
      for (int ni = 0; ni < 4; ++ni)                                          \
        acc[mi][ni] = __builtin_amdgcn_mfma_f32_16x16x32_bf16(                \
            af_, BF[ni], acc[mi][ni], 0, 0, 0);                               \
    }                                                                         \
  } while (0)

__global__ __launch_bounds__(256, 3) void qlin_gemm9(
    const ushort* __restrict__ WSX, const ushort* __restrict__ WSB,
    const float* __restrict__ bias, float* __restrict__ Y)
{
  // 2048 blocks = 256 m x 8 n; XCD-bijective swizzle (2048%8==0), n fastest.
  const int per = 2048 >> 3;  // 256
  const int bid = (int)blockIdx.x;
  const int swz = (bid & 7) * per + (bid >> 3);
  const int mblk = swz >> 3;       // 0..255
  const int nblk = swz & 7;        // 0..7
  const int m0 = mblk << 7;
  const int n0 = nblk << 7;
  const int a_idx = nblk >> 1;     // 256-col source quadrant

  const int tid = (int)threadIdx.x;
  const int lane = tid & 63;
  const int wv = tid >> 6;         // 0..3
  const int wr = wv >> 1;          // wave row 0/1
  const int wc = wv & 1;           // wave col 0/1
  const int fmB = mblk << 3;       // block's global row-frag base (8 frags)
  const int frW = wr << 2;         // wave's local row-frag base (0/4)
  const int cb0 = ((nblk & 1) << 3) + (wc << 2);  // B col-frag base

  __shared__ __align__(16) ushort smA[3 * 8 * 512];  // 3 bufs x 8 frags x 1KB
  ushort* const lbuf0 = smA;
  ushort* const lbuf1 = smA + 8 * 512;
  ushort* const lbuf2 = smA + 16 * 512;

  bf16x8 bq0[4], bq1[4], bq2[4];
  f32x4 acc[4][4];
#pragma unroll
  for (int i = 0; i < 4; ++i)
#pragma unroll
    for (int j = 0; j < 4; ++j) acc[i][j] = (f32x4)(0.0f);

  // prologue: slabs 0,1 in flight (12 vmem outstanding)
  STAGE9(0, lbuf0); LOADB9(0, bq0);
  STAGE9(1, lbuf1); LOADB9(1, bq1);

  // steady state: 10 iterations x 3 slabs; wait vmcnt(6) per slab.
#pragma unroll 1
  for (int s = 0; s < 30; s += 3) {
    WAIT6_BAR();                                 // slab s landed
    STAGE9(s + 2, lbuf2); LOADB9(s + 2, bq2);    // buf2 last read at slab s-1
    SGN9(s, bq0); COMPUTE9(lbuf0, bq0);
    WAIT6_BAR();
    STAGE9(s + 3, lbuf0); LOADB9(s + 3, bq0);
    SGN9(s + 1, bq1); COMPUTE9(lbuf1, bq1);
    WAIT6_BAR();
    STAGE9(s + 4, lbuf1); LOADB9(s + 4, bq1);
    SGN9(s + 2, bq2); COMPUTE9(lbuf2, bq2);
  }
  // tail: slab 30 (buf0/bq0), slab 31 (buf1/bq1)
  WAIT6_BAR();
  SGN9(30, bq0); COMPUTE9(lbuf0, bq0);
  WAIT0_BAR();
  SGN9(31, bq1); COMPUTE9(lbuf1, bq1);

  // epilogue: C/D layout col = lane&15, row = (lane>>4)*4 + reg  [m89-verified]
#pragma unroll
  for (int ni = 0; ni < 4; ++ni) {
    const int col = n0 + (wc << 6) + (ni << 4) + (lane & 15);
    const float bv = bias[col];
#pragma unroll
    for (int mi = 0; mi < 4; ++mi) {
      const int r0e = m0 + (wr << 6) + (mi << 4) + ((lane >> 4) << 2);
#pragma unroll
      for (int j = 0; j < 4; ++j)
        Y[(size_t)(r0e + j) * N_TOTAL + col] = acc[mi][ni][j] + bv;
    }
  }
}

// ===========================================================================
// Mid-tier (round-7 champion structure): 256x256 tile, B frag-direct, A LDS.
// ===========================================================================
#define BM2 256
#define BN2 256
#define BK2 64
#define NT2 512
#define NSTEPS2 (K_TOTAL / BK2)

#define LOAD_A2(kk) do {                                                      \
    _Pragma("unroll")                                                         \
    for (int cc = 0; cc < 4; ++cc) {                                          \
      const float* pa_ = X + (size_t)(m0 + r0 + 64 * cc) * K_TOTAL + (kk) + k0;\
      rA[2 * cc]     = *(const f32x4*)pa_;                                    \
      rA[2 * cc + 1] = *(const f32x4*)(pa_ + 4);                              \
    }                                                                         \
  } while (0)

#define COMMIT_A2(dst) do {                                                   \
    _Pragma("unroll")                                                         \
    for (int cc = 0; cc < 4; ++cc) {                                          \
      u32x4 va_;                                                              \
      va_[0] = pk2(rA[2 * cc][0], rA[2 * cc][1]);                             \
      va_[1] = pk2(rA[2 * cc][2], rA[2 * cc][3]);                             \
      va_[2] = pk2(rA[2 * cc + 1][0], rA[2 * cc + 1][1]);                     \
      va_[3] = pk2(rA[2 * cc + 1][2], rA[2 * cc + 1][3]);                     \
      *(u32x4*)((dst) + sbase + 8192 * cc) = va_;                             \
    }                                                                         \
  } while (0)

#define LOAD_B2(kk) do {                                                      \
    const int bsel_ = (kk) >> 8;                                              \
    const int si_ = a_idx ^ bsel_;                                            \
    const int kbq_ = ((kk) & 255) >> 5;                                       \
    const ushort* fb_ = WS + ((size_t)((si_ * 16 + wc4) * 8 + kbq_)) * 512    \
                        + lane * 8;                                           \
    _Pragma("unroll")                                                         \
    for (int ks = 0; ks < 2; ++ks)                                            \
      _Pragma("unroll")                                                       \
      for (int ni = 0; ni < 4; ++ni)                                          \
        bq[ks * 4 + ni] = *(const bf16x8*)(fb_ + (ni * 8 + ks) * 512);        \
    if ((0x284Eu >> ((a_idx << 2) | bsel_)) & 1u) {                           \
      _Pragma("unroll")                                                       \
      for (int f = 0; f < 8; ++f) {                                           \
        u32x4 u_ = __builtin_bit_cast(u32x4, bq[f]);                          \
        u_[0] ^= 0x80008000u; u_[1] ^= 0x80008000u;                           \
        u_[2] ^= 0x80008000u; u_[3] ^= 0x80008000u;                           \
        bq[f] = __builtin_bit_cast(bf16x8, u_);                               \
      }                                                                       \
    }                                                                         \
  } while (0)

#define COMPUTE2(src) do {                                                    \
    _Pragma("unroll")                                                         \
    for (int ks = 0; ks < 2; ++ks) {                                          \
      _Pragma("unroll")                                                       \
      for (int mi = 0; mi < 8; ++mi) {                                        \
        const int row_ = frow_a0 + (mi << 4);                                 \
        const int kb_ = (ks << 6) + fkb;                                      \
        bf16x8 af_ = *(const bf16x8*)((src) + row_ * (BK2 * 2)                \
                                      + (kb_ ^ ((row_ & 7) << 4)));           \
        _Pragma("unroll")                                                     \
        for (int ni = 0; ni < 4; ++ni)                                        \
          acc[mi][ni] = __builtin_amdgcn_mfma_f32_16x16x32_bf16(              \
              af_, bq[ks * 4 + ni], acc[mi][ni], 0, 0, 0);                    \
      }                                                                       \
    }                                                                         \
  } while (0)

__global__ __launch_bounds__(NT2, 2) void qlin_gemm2(
    const float* __restrict__ X, const ushort* __restrict__ WS,
    const float* __restrict__ bias, float* __restrict__ Y)
{
  const int per = ((M_TOTAL / BM2) * (N_TOTAL / BN2)) >> 3;  // 64
  const int bid = (int)blockIdx.x;
  const int swz = (bid & 7) * per + (bid >> 3);
  const int m0 = (swz >> 2) * BM2;
  const int nblk = swz & 3;
  const int n0 = nblk * BN2;
  const int a_idx = nblk;

  const int tid = (int)threadIdx.x;
  const int lane = tid & 63;
  const int wave = tid >> 6;
  const int wm = (wave >> 2) << 7;
  const int wc4 = (wave & 3) << 2;

  __shared__ __align__(16) ushort smA[2 * BM2 * BK2];  // 64 KB dbuf
  char* const cS = (char*)smA;

  const int r0 = tid >> 3;
  const int k0 = (tid & 7) << 3;
  const int sbase = r0 * (BK2 * 2) + ((k0 * 2) ^ ((r0 & 7) << 4));

  f32x4 rA[8];
  bf16x8 bq[8];
  f32x4 acc[8][4];
#pragma unroll
  for (int i = 0; i < 8; ++i)
#pragma unroll
    for (int j = 0; j < 4; ++j) acc[i][j] = (f32x4)(0.0f);

  const int frow_a0 = wm + (lane & 15);
  const int fkb = (lane >> 4) << 4;

  LOAD_A2(0);
  COMMIT_A2(cS);
  LOAD_A2(BK2);
  SOFT_BARRIER();

#pragma unroll 1
  for (int k = 0; k < NSTEPS2; ++k) {
    char* const rbuf = cS + ((k & 1) << 15);
    char* const wbuf = cS + (((k + 1) & 1) << 15);
    COMMIT_A2(wbuf);
    LOAD_B2(k * BK2);
    if (k + 2 < NSTEPS2) LOAD_A2((k + 2) * BK2);
    COMPUTE2(rbuf);
    SOFT_BARRIER();
  }

#pragma unroll
  for (int ni = 0; ni < 4; ++ni) {
    const int col = n0 + (wc4 << 4) + (ni << 4) + (lane & 15);
    const float bv = bias[col];
#pragma unroll
    for (int mi = 0; mi < 8; ++mi) {
      const int r0e = m0 + wm + (mi << 4) + ((lane >> 4) << 2);
#pragma unroll
      for (int j = 0; j < 4; ++j)
        Y[(size_t)(r0e + j) * N_TOTAL + col] = acc[mi][ni][j] + bv;
    }
  }
}

// ===========================================================================
// No-ws fallback (round-6, 126 us).
// ===========================================================================
#define BM 128
#define BN 128
#define BK 64
#define NTHREADS 256
#define NSTEPS (K_TOTAL / BK)

#define LOAD_TILE(kk) do {                                                    \
    const int si_ = a_idx ^ ((kk) >> 8);                                      \
    const float* Bsrc_ = (si_ == 0) ? Rm : (si_ == 1) ? Im                    \
                       : (si_ == 2) ? Jm : Km;                                \
    const int kloc_ = (kk) & 255;                                             \
    _Pragma("unroll")                                                         \
    for (int cc = 0; cc < 4; ++cc) {                                          \
      const float* pa_ = X + (size_t)(m0 + r0 + 32 * cc) * K_TOTAL + (kk) + k0;\
      rA[2 * cc]     = *(const f32x4*)pa_;                                    \
      rA[2 * cc + 1] = *(const f32x4*)(pa_ + 4);                              \
      const float* pb_ = Bsrc_ + (o_src + r0 + 32 * cc) * 256 + kloc_ + k0;   \
      rB[2 * cc]     = *(const f32x4*)pb_;                                    \
      rB[2 * cc + 1] = *(const f32x4*)(pb_ + 4);                              \
    }                                                                         \
  } while (0)

#define COMMIT_TILE(kk, dst) do {                                             \
    const uint neg_ = (0x284Eu >> ((a_idx << 2) | ((kk) >> 8))) & 1u;         \
    _Pragma("unroll")                                                         \
    for (int cc = 0; cc < 4; ++cc) {                                          \
      u32x4 va_;                                                              \
      va_[0] = pk2(rA[2 * cc][0], rA[2 * cc][1]);                             \
      va_[1] = pk2(rA[2 * cc][2], rA[2 * cc][3]);                             \
      va_[2] = pk2(rA[2 * cc + 1][0], rA[2 * cc + 1][1]);                     \
      va_[3] = pk2(rA[2 * cc + 1][2], rA[2 * cc + 1][3]);                     \
      *(u32x4*)((dst) + sbase + 4096 * cc) = va_;                             \
    }                                                                         \
    if (neg_) {                                                               \
      _Pragma("unroll")                                                       \
      for (int cc = 0; cc < 4; ++cc) {                                        \
        u32x4 vb_;                                                            \
        vb_[0] = pk2(-rB[2 * cc][0], -rB[2 * cc][1]);                         \
        vb_[1] = pk2(-rB[2 * cc][2], -rB[2 * cc][3]);                         \
        vb_[2] = pk2(-rB[2 * cc + 1][0], -rB[2 * cc + 1][1]);                 \
        vb_[3] = pk2(-rB[2 * cc + 1][2], -rB[2 * cc + 1][3]);                 \
        *(u32x4*)((dst) + 16384 + sbase + 4096 * cc) = vb_;                   \
      }                                                                       \
    } else {                                                                  \
      _Pragma("unroll")                                                       \
      for (int cc = 0; cc < 4; ++cc) {                                        \
        u32x4 vb_;                                                            \
        vb_[0] = pk2(rB[2 * cc][0], rB[2 * cc][1]);                           \
        vb_[1] = pk2(rB[2 * cc][2], rB[2 * cc][3]);                           \
        vb_[2] = pk2(rB[2 * cc + 1][0], rB[2 * cc + 1][1]);                   \
        vb_[3] = pk2(rB[2 * cc + 1][2], rB[2 * cc + 1][3]);                   \
        *(u32x4*)((dst) + 16384 + sbase + 4096 * cc) = vb_;                   \
      }                                                                       \
    }                                                                         \
  } while (0)

#define COMPUTE_TILE(src) do {                                                \
    _Pragma("unroll")                                                         \
    for (int ks = 0; ks < 2; ++ks) {                                          \
      const int kb_ = (ks << 6) + fkb;                                        \
      bf16x8 af_[4], bf_[4];                                                  \
      _Pragma("unroll")                                                       \
      for (int mi = 0; mi < 4; ++mi) {                                        \
        const int row_ = frow_a0 + (mi << 4);                                 \
        af_[mi] = *(const bf16x8*)((src) + row_ * (BK * 2)                    \
                                   + (kb_ ^ ((row_ & 7) << 4)));              \
      }                                                                       \
      _Pragma("unroll")                                                       \
      for (int ni = 0; ni < 4; ++ni) {                                        \
        const int row_ = frow_b0 + (ni << 4);                                 \
        bf_[ni] = *(const bf16x8*)((src) + 16384 + row_ * (BK * 2)            \
                                   + (kb_ ^ ((row_ & 7) << 4)));              \
      }                                                                       \
      _Pragma("unroll")                                                       \
      for (int mi = 0; mi < 4; ++mi)                                          \
        _Pragma("unroll")                                                     \
        for (int ni = 0; ni < 4; ++ni)                                        \
          acc[mi][ni] = __builtin_amdgcn_mfma_f32_16x16x32_bf16(              \
              af_[mi], bf_[ni], acc[mi][ni], 0, 0, 0);                        \
    }                                                                         \
  } while (0)

__global__ __launch_bounds__(NTHREADS, 2) void qlin_gemm(
    const float* __restrict__ X, const float* __restrict__ Rm,
    const float* __restrict__ Im, const float* __restrict__ Jm,
    const float* __restrict__ Km, const float* __restrict__ bias,
    float* __restrict__ Y)
{
  const int per = ((M_TOTAL / BM) * (N_TOTAL / BN)) >> 3;
  const int bid = (int)blockIdx.x;
  const int swz = (bid & 7) * per + (bid >> 3);
  const int m0 = (swz >> 3) * BM;
  const int n0 = (swz & 7) * BN;

  const int tid = (int)threadIdx.x;
  const int lane = tid & 63;
  const int wave = tid >> 6;
  const int wm = (wave >> 1) << 6;
  const int wn = (wave & 1) << 6;

  __shared__ __align__(16) ushort sm[2 * 2 * BM * BK];
  char* const cS = (char*)sm;

  const int a_idx = n0 >> 8;
  const int o_src = n0 & 255;

  const int r0 = tid >> 3;
  const int k0 = (tid & 7) << 3;
  const int sbase = r0 * (BK * 2) + ((k0 * 2) ^ ((r0 & 7) << 4));

  f32x4 rA[8], rB[8];
  f32x4 acc[4][4];
#pragma unroll
  for (int i = 0; i < 4; ++i)
#pragma unroll
    for (int j = 0; j < 4; ++j) acc[i][j] = (f32x4)(0.0f);

  const int frow_a0 = wm + (lane & 15);
  const int frow_b0 = wn + (lane & 15);
  const int fkb = (lane >> 4) << 4;

  LOAD_TILE(0);
  COMMIT_TILE(0, cS);
  LOAD_TILE(BK);
  SOFT_BARRIER();

#pragma unroll 1
  for (int k = 0; k < NSTEPS; ++k) {
    char* const rbuf = cS + ((k & 1) << 15);
    char* const wbuf = cS + (((k + 1) & 1) << 15);
    if (k + 1 < NSTEPS) COMMIT_TILE((k + 1) * BK, wbuf);
    if (k + 2 < NSTEPS) LOAD_TILE((k + 2) * BK);
    COMPUTE_TILE(rbuf);
    SOFT_BARRIER();
  }

#pragma unroll
  for (int ni = 0; ni < 4; ++ni) {
    const int col = n0 + wn + (ni << 4) + (lane & 15);
    const float bv = bias[col];
#pragma unroll
    for (int mi = 0; mi < 4; ++mi) {
      const int r0e = m0 + wm + (mi << 4) + ((lane >> 4) << 2);
#pragma unroll
      for (int j = 0; j < 4; ++j)
        Y[(size_t)(r0e + j) * N_TOTAL + col] = acc[mi][ni][j] + bv;
    }
  }
}

extern "C" void kernel_launch(void* const* d_in, const int* in_sizes, int n_in,
                              void* d_out, int out_size, void* d_ws, size_t ws_size,
                              hipStream_t stream) {
  const float* X = (const float*)d_in[0];
  const float* Rm = (const float*)d_in[1];
  const float* Im = (const float*)d_in[2];
  const float* Jm = (const float*)d_in[3];
  const float* Km = (const float*)d_in[4];
  const float* bias = (const float*)d_in[5];
  float* Y = (float*)d_out;

  const size_t needB = (size_t)4 * 256 * 256 * 2;            // 512 KB
  const size_t needX = (size_t)M_TOTAL * K_TOTAL * 2;        // 64 MB

  if (ws_size >= needX + needB) {
    ushort* wsx = (ushort*)d_ws;
    ushort* wsb = wsx + (size_t)M_TOTAL * K_TOTAL;
    conv_x<<<dim3(16384), dim3(256), 0, stream>>>(X, wsx);
    conv_b<<<dim3(128), dim3(256), 0, stream>>>(Rm, Im, Jm, Km, wsb);
    qlin_gemm9<<<dim3(2048), dim3(256), 0, stream>>>(wsx, wsb, bias, Y);
  } else if (ws_size >= needB) {
    ushort* wsb = (ushort*)d_ws;
    conv_b<<<dim3(128), dim3(256), 0, stream>>>(Rm, Im, Jm, Km, wsb);
    qlin_gemm2<<<dim3((M_TOTAL / BM2) * (N_TOTAL / BN2)), dim3(NT2), 0, stream>>>(
        X, wsb, bias, Y);
  } else {
    qlin_gemm<<<dim3((M_TOTAL / BM) * (N_TOTAL / BN)), dim3(NTHREADS), 0, stream>>>(
        X, Rm, Im, Jm, Km, bias, Y);
  }
}

// Round 22
// 115.065 us; speedup vs baseline: 1.1530x; 1.0133x over previous
//
#include <hip/hip_runtime.h>
#include <hip/hip_bf16.h>

typedef __attribute__((ext_vector_type(4))) float f32x4;
typedef __attribute__((ext_vector_type(4))) uint u32x4;
typedef __attribute__((ext_vector_type(8))) short bf16x8;

#define M_TOTAL 32768
#define N_TOTAL 1024
#define K_TOTAL 1024

__device__ __forceinline__ uint pk2(float a, float b) {
  __hip_bfloat162 h = __float22bfloat162_rn(make_float2(a, b));  // v_cvt_pk_bf16_f32
  uint u;
  __builtin_memcpy(&u, &h, 4);
  return u;
}

// Non-draining barrier (fallback kernels only).
#define SOFT_BARRIER() do {                                                   \
    __builtin_amdgcn_sched_barrier(0);                                        \
    asm volatile("s_waitcnt lgkmcnt(0)" ::: "memory");                        \
    __builtin_amdgcn_s_barrier();                                             \
    __builtin_amdgcn_sched_barrier(0);                                        \
  } while (0)

// Counted-vmcnt barriers (gemm9): wait only the OLDEST slab's 6 vmem ops
// (2 gload_lds + 4 B-loads); the next slab's 6 stay in flight (T4/m218).
#define WAIT6_BAR() do {                                                      \
    __builtin_amdgcn_sched_barrier(0);                                        \
    asm volatile("s_waitcnt vmcnt(6)" ::: "memory");                          \
    __builtin_amdgcn_s_barrier();                                             \
    __builtin_amdgcn_sched_barrier(0);                                        \
  } while (0)
#define WAIT0_BAR() do {                                                      \
    __builtin_amdgcn_sched_barrier(0);                                        \
    asm volatile("s_waitcnt vmcnt(0)" ::: "memory");                          \
    __builtin_amdgcn_s_barrier();                                             \
    __builtin_amdgcn_sched_barrier(0);                                        \
  } while (0)

// ===========================================================================
// Merged pre-pass: blocks 0..16383 convert X (32768x1024 f32) -> frag-major
// bf16 wsx (64 MB); blocks 16384..16511 convert the 4 S-matrices -> frag-major
// bf16 wsb (512 KB, at wsx + 32M elems). Bodies byte-identical to the
// r10-r21-verified conv_x / conv_b; branch is block-uniform. Saves one
// graph launch + lets conv_b ride conv_x's tail.
// ===========================================================================
__global__ __launch_bounds__(256) void conv_xb(
    const float* __restrict__ X, const float* __restrict__ Rm,
    const float* __restrict__ Im, const float* __restrict__ Jm,
    const float* __restrict__ Km, ushort* __restrict__ wsx)
{
  const int bidx = (int)blockIdx.x;
  if (bidx < 16384) {
    // ---- conv_x body (verified r10-r21) ----
    const int g = bidx * 256 + (int)threadIdx.x;
    const int wid = g >> 6;   // (fm 0..2047, kb 0..31)
    const int lane = g & 63;
    const int fm = wid >> 5;
    const int kb = wid & 31;
    const float* p = X + (size_t)(fm * 16 + (lane & 15)) * K_TOTAL
                       + kb * 32 + (lane >> 4) * 8;
    f32x4 lo = *(const f32x4*)p;
    f32x4 hi = *(const f32x4*)(p + 4);
    u32x4 v;
    v[0] = pk2(lo[0], lo[1]); v[1] = pk2(lo[2], lo[3]);
    v[2] = pk2(hi[0], hi[1]); v[3] = pk2(hi[2], hi[3]);
    *(u32x4*)(wsx + (size_t)wid * 512 + lane * 8) = v;
  } else {
    // ---- conv_b body (verified r7-r21) ----
    ushort* const ws = wsx + (size_t)M_TOTAL * K_TOTAL;  // wsb
    const int slot = (bidx - 16384) * 256 + (int)threadIdx.x;  // 0..32767
    const int lane = slot & 63;
    const int kb = (slot >> 6) & 7;
    const int cb = (slot >> 9) & 15;
    const int si = slot >> 13;
    const float* S = (si == 0) ? Rm : (si == 1) ? Im : (si == 2) ? Jm : Km;
    const float* p = S + (cb * 16 + (lane & 15)) * 256 + kb * 32 + (lane >> 4) * 8;
    f32x4 lo = *(const f32x4*)p;
    f32x4 hi = *(const f32x4*)(p + 4);
    u32x4 v;
    v[0] = pk2(lo[0], lo[1]); v[1] = pk2(lo[2], lo[3]);
    v[2] = pk2(hi[0], hi[1]); v[3] = pk2(hi[2], hi[3]);
    *(u32x4*)(ws + (size_t)slot * 8) = v;
  }
}

// Standalone conv_b for the mid-tier fallback (wsb-only workspaces).
__global__ __launch_bounds__(256) void conv_b(
    const float* __restrict__ Rm, const float* __restrict__ Im,
    const float* __restrict__ Jm, const float* __restrict__ Km,
    ushort* __restrict__ ws)
{
  const int slot = blockIdx.x * 256 + (int)threadIdx.x;  // 0..32767
  const int lane = slot & 63;
  const int kb = (slot >> 6) & 7;
  const int cb = (slot >> 9) & 15;
  const int si = slot >> 13;
  const float* S = (si == 0) ? Rm : (si == 1) ? Im : (si == 2) ? Jm : Km;
  const float* p = S + (cb * 16 + (lane & 15)) * 256 + kb * 32 + (lane >> 4) * 8;
  f32x4 lo = *(const f32x4*)p;
  f32x4 hi = *(const f32x4*)(p + 4);
  u32x4 v;
  v[0] = pk2(lo[0], lo[1]); v[1] = pk2(lo[2], lo[3]);
  v[2] = pk2(hi[0], hi[1]); v[3] = pk2(hi[2], hi[3]);
  *(u32x4*)(ws + (size_t)slot * 8) = v;
}

// ===========================================================================
// Pass 2 (gemm9 — CHAMPION, r14/r19/r21: 88-96 us, MfmaUtil ~31%, no spill;
// r20 proved setprio REGRESSES this kernel — omitted):
// block 128x128, 4 waves 2x2 (wave 64x64, acc=64 AGPR). K-slab=32.
// A: global_load_lds frag-major wsx -> TRIPLE-buffered shared LDS (24 KB),
//    2 gload_lds/wave/slab (zero VGPR transit). B: frag-direct from
//    L2-resident wsb, triple-buffered regs (48 VGPR — register-feasible max;
//    64 VGPR spills, r17/r18). Sign via bf16 sign-bit XOR.
// Counted vmcnt(6) + barrier per slab — never drains in-loop (T4/m218).
// ===========================================================================
#define STAGE9(s, lb) do {                                                    \
    _Pragma("unroll")                                                         \
    for (int j = 0; j < 2; ++j) {                                             \
      const int f_ = (wv << 1) + j;                                           \
      const ushort* s_ = WSX + ((size_t)(fmB + f_) * 32 + (s)) * 512          \
                         + lane * 8;                                          \
      __builtin_amdgcn_global_load_lds((const uint*)s_,                       \
                                       (uint*)((lb) + f_ * 512), 16, 0, 0);   \
    }                                                                         \
  } while (0)

#define LOADB9(s, BF) do {                                                    \
    const int si_ = a_idx ^ ((s) >> 3);                                       \
    const int kbq_ = (s) & 7;                                                 \
    _Pragma("unroll")                                                         \
    for (int ni = 0; ni < 4; ++ni)                                            \
      BF[ni] = *(const bf16x8*)(                                              \
          WSB + ((size_t)((si_ * 16 + cb0 + ni) * 8 + kbq_)) * 512            \
          + lane * 8);                                                        \
  } while (0)

#define SGN9(s, BF) do {                                                      \
    if ((0x284Eu >> ((a_idx << 2) | ((s) >> 3))) & 1u) {                      \
      _Pragma("unroll")                                                       \
      for (int f = 0; f < 4; ++f) {                                           \
        u32x4 u_ = __builtin_bit_cast(u32x4, BF[f]);                          \
        u_[0] ^= 0x80008000u; u_[1] ^= 0x80008000u;                           \
        u_[2] ^= 0x80008000u; u_[3] ^= 0x80008000u;                           \
        BF[f] = __builtin_bit_cast(bf16x8, u_);                               \
      }                                                                       \
    }                                                                         \
  } while (0)

#define COMPUTE9(lb, BF) do {                                                 \
    _Pragma("unroll")                                                         \
    for (int mi = 0; mi < 4; ++mi) {                                          \
      bf16x8 af_ = *(const bf16x8*)((lb) + (frW + mi) * 512 + lane * 8);      \
      _Pragma("unroll")                                                       \
      for (int ni = 0; ni < 4; ++ni)                                          \
        acc[mi][ni] = __builtin_amdgcn_mfma_f32_16x16x32_bf16(                \
            af_, BF[ni], acc[mi][ni], 0, 0, 0);                               \
    }                                                                         \
  } while (0)

__global__ __launch_bounds__(256, 3) void qlin_gemm9(
    const ushort* __restrict__ WSX, const ushort* __restrict__ WSB,
    const float* __restrict__ bias, float* __restrict__ Y)
{
  // 2048 blocks = 256 m x 8 n; XCD-bijective swizzle (2048%8==0), n fastest.
  const int per = 2048 >> 3;  // 256
  const int bid = (int)blockIdx.x;
  const int swz = (bid & 7) * per + (bid >> 3);
  const int mblk = swz >> 3;       // 0..255
  const int nblk = swz & 7;        // 0..7
  const int m0 = mblk << 7;
  const int n0 = nblk << 7;
  const int a_idx = nblk >> 1;     // 256-col source quadrant

  const int tid = (int)threadIdx.x;
  const int lane = tid & 63;
  const int wv = tid >> 6;         // 0..3
  const int wr = wv >> 1;          // wave row 0/1
  const int wc = wv & 1;           // wave col 0/1
  const int fmB = mblk << 3;       // block's global row-frag base (8 frags)
  const int frW = wr << 2;         // wave's local row-frag base (0/4)
  const int cb0 = ((nblk & 1) << 3) + (wc << 2);  // B col-frag base

  __shared__ __align__(16) ushort smA[3 * 8 * 512];  // 3 bufs x 8 frags x 1KB
  ushort* const lbuf0 = smA;
  ushort* const lbuf1 = smA + 8 * 512;
  ushort* const lbuf2 = smA + 16 * 512;

  bf16x8 bq0[4], bq1[4], bq2[4];
  f32x4 acc[4][4];
#pragma unroll
  for (int i = 0; i < 4; ++i)
#pragma unroll
    for (int j = 0; j < 4; ++j) acc[i][j] = (f32x4)(0.0f);

  // prologue: slabs 0,1 in flight (12 vmem outstanding)
  STAGE9(0, lbuf0); LOADB9(0, bq0);
  STAGE9(1, lbuf1); LOADB9(1, bq1);

  // steady state: 10 iterations x 3 slabs; wait vmcnt(6) per slab.
#pragma unroll 1
  for (int s = 0; s < 30; s += 3) {
    WAIT6_BAR();                                 // slab s landed
    STAGE9(s + 2, lbuf2); LOADB9(s + 2, bq2);    // buf2 last read at slab s-1
    SGN9(s, bq0); COMPUTE9(lbuf0, bq0);
    WAIT6_BAR();
    STAGE9(s + 3, lbuf0); LOADB9(s + 3, bq0);
    SGN9(s + 1, bq1); COMPUTE9(lbuf1, bq1);
    WAIT6_BAR();
    STAGE9(s + 4, lbuf1); LOADB9(s + 4, bq1);
    SGN9(s + 2, bq2); COMPUTE9(lbuf2, bq2);
  }
  // tail: slab 30 (buf0/bq0), slab 31 (buf1/bq1)
  WAIT6_BAR();
  SGN9(30, bq0); COMPUTE9(lbuf0, bq0);
  WAIT0_BAR();
  SGN9(31, bq1); COMPUTE9(lbuf1, bq1);

  // epilogue: C/D layout col = lane&15, row = (lane>>4)*4 + reg  [m89-verified]
#pragma unroll
  for (int ni = 0; ni < 4; ++ni) {
    const int col = n0 + (wc << 6) + (ni << 4) + (lane & 15);
    const float bv = bias[col];
#pragma unroll
    for (int mi = 0; mi < 4; ++mi) {
      const int r0e = m0 + (wr << 6) + (mi << 4) + ((lane >> 4) << 2);
#pragma unroll
      for (int j = 0; j < 4; ++j)
        Y[(size_t)(r0e + j) * N_TOTAL + col] = acc[mi][ni][j] + bv;
    }
  }
}

// ===========================================================================
// Mid-tier (round-7 champion structure): 256x256 tile, B frag-direct, A LDS.
// ===========================================================================
#define BM2 256
#define BN2 256
#define BK2 64
#define NT2 512
#define NSTEPS2 (K_TOTAL / BK2)

#define LOAD_A2(kk) do {                                                      \
    _Pragma("unroll")                                                         \
    for (int cc = 0; cc < 4; ++cc) {                                          \
      const float* pa_ = X + (size_t)(m0 + r0 + 64 * cc) * K_TOTAL + (kk) + k0;\
      rA[2 * cc]     = *(const f32x4*)pa_;                                    \
      rA[2 * cc + 1] = *(const f32x4*)(pa_ + 4);                              \
    }                                                                         \
  } while (0)

#define COMMIT_A2(dst) do {                                                   \
    _Pragma("unroll")                                                         \
    for (int cc = 0; cc < 4; ++cc) {                                          \
      u32x4 va_;                                                              \
      va_[0] = pk2(rA[2 * cc][0], rA[2 * cc][1]);                             \
      va_[1] = pk2(rA[2 * cc][2], rA[2 * cc][3]);                             \
      va_[2] = pk2(rA[2 * cc + 1][0], rA[2 * cc + 1][1]);                     \
      va_[3] = pk2(rA[2 * cc + 1][2], rA[2 * cc + 1][3]);                     \
      *(u32x4*)((dst) + sbase + 8192 * cc) = va_;                             \
    }                                                                         \
  } while (0)

#define LOAD_B2(kk) do {                                                      \
    const int bsel_ = (kk) >> 8;                                              \
    const int si_ = a_idx ^ bsel_;                                            \
    const int kbq_ = ((kk) & 255) >> 5;                                       \
    const ushort* fb_ = WS + ((size_t)((si_ * 16 + wc4) * 8 + kbq_)) * 512    \
                        + lane * 8;                                           \
    _Pragma("unroll")                                                         \
    for (int ks = 0; ks < 2; ++ks)                                            \
      _Pragma("unroll")                                                       \
      for (int ni = 0; ni < 4; ++ni)                                          \
        bq[ks * 4 + ni] = *(const bf16x8*)(fb_ + (ni * 8 + ks) * 512);        \
    if ((0x284Eu >> ((a_idx << 2) | bsel_)) & 1u) {                           \
      _Pragma("unroll")                                                       \
      for (int f = 0; f < 8; ++f) {                                           \
        u32x4 u_ = __builtin_bit_cast(u32x4, bq[f]);                          \
        u_[0] ^= 0x80008000u; u_[1] ^= 0x80008000u;                           \
        u_[2] ^= 0x80008000u; u_[3] ^= 0x80008000u;                           \
        bq[f] = __builtin_bit_cast(bf16x8, u_);                               \
      }                                                                       \
    }                                                                         \
  } while (0)

#define COMPUTE2(src) do {                                                    \
    _Pragma("unroll")                                                         \
    for (int ks = 0; ks < 2; ++ks) {                                          \
      _Pragma("unroll")                                                       \
      for (int mi = 0; mi < 8; ++mi) {                                        \
        const int row_ = frow_a0 + (mi << 4);                                 \
        const int kb_ = (ks << 6) + fkb;                                      \
        bf16x8 af_ = *(const bf16x8*)((src) + row_ * (BK2 * 2)                \
                                      + (kb_ ^ ((row_ & 7) << 4)));           \
        _Pragma("unroll")                                                     \
        for (int ni = 0; ni < 4; ++ni)                                        \
          acc[mi][ni] = __builtin_amdgcn_mfma_f32_16x16x32_bf16(              \
              af_, bq[ks * 4 + ni], acc[mi][ni], 0, 0, 0);                    \
      }                                                                       \
    }                                                                         \
  } while (0)

__global__ __launch_bounds__(NT2, 2) void qlin_gemm2(
    const float* __restrict__ X, const ushort* __restrict__ WS,
    const float* __restrict__ bias, float* __restrict__ Y)
{
  const int per = ((M_TOTAL / BM2) * (N_TOTAL / BN2)) >> 3;  // 64
  const int bid = (int)blockIdx.x;
  const int swz = (bid & 7) * per + (bid >> 3);
  const int m0 = (swz >> 2) * BM2;
  const int nblk = swz & 3;
  const int n0 = nblk * BN2;
  const int a_idx = nblk;

  const int tid = (int)threadIdx.x;
  const int lane = tid & 63;
  const int wave = tid >> 6;
  const int wm = (wave >> 2) << 7;
  const int wc4 = (wave & 3) << 2;

  __shared__ __align__(16) ushort smA[2 * BM2 * BK2];  // 64 KB dbuf
  char* const cS = (char*)smA;

  const int r0 = tid >> 3;
  const int k0 = (tid & 7) << 3;
  const int sbase = r0 * (BK2 * 2) + ((k0 * 2) ^ ((r0 & 7) << 4));

  f32x4 rA[8];
  bf16x8 bq[8];
  f32x4 acc[8][4];
#pragma unroll
  for (int i = 0; i < 8; ++i)
#pragma unroll
    for (int j = 0; j < 4; ++j) acc[i][j] = (f32x4)(0.0f);

  const int frow_a0 = wm + (lane & 15);
  const int fkb = (lane >> 4) << 4;

  LOAD_A2(0);
  COMMIT_A2(cS);
  LOAD_A2(BK2);
  SOFT_BARRIER();

#pragma unroll 1
  for (int k = 0; k < NSTEPS2; ++k) {
    char* const rbuf = cS + ((k & 1) << 15);
    char* const wbuf = cS + (((k + 1) & 1) << 15);
    COMMIT_A2(wbuf);
    LOAD_B2(k * BK2);
    if (k + 2 < NSTEPS2) LOAD_A2((k + 2) * BK2);
    COMPUTE2(rbuf);
    SOFT_BARRIER();
  }

#pragma unroll
  for (int ni = 0; ni < 4; ++ni) {
    const int col = n0 + (wc4 << 4) + (ni << 4) + (lane & 15);
    const float bv = bias[col];
#pragma unroll
    for (int mi = 0; mi < 8; ++mi) {
      const int r0e = m0 + wm + (mi << 4) + ((lane >> 4) << 2);
#pragma unroll
      for (int j = 0; j < 4; ++j)
        Y[(size_t)(r0e + j) * N_TOTAL + col] = acc[mi][ni][j] + bv;
    }
  }
}

// ===========================================================================
// No-ws fallback (round-6, 126 us).
// ===========================================================================
#define BM 128
#define BN 128
#define BK 64
#define NTHREADS 256
#define NSTEPS (K_TOTAL / BK)

#define LOAD_TILE(kk) do {                                                    \
    const int si_ = a_idx ^ ((kk) >> 8);                                      \
    const float* Bsrc_ = (si_ == 0) ? Rm : (si_ == 1) ? Im                    \
                       : (si_ == 2) ? Jm : Km;                                \
    const int kloc_ = (kk) & 255;                                             \
    _Pragma("unroll")                                                         \
    for (int cc = 0; cc < 4; ++cc) {                                          \
      const float* pa_ = X + (size_t)(m0 + r0 + 32 * cc) * K_TOTAL + (kk) + k0;\
      rA[2 * cc]     = *(const f32x4*)pa_;                                    \
      rA[2 * cc + 1] = *(const f32x4*)(pa_ + 4);                              \
      const float* pb_ = Bsrc_ + (o_src + r0 + 32 * cc) * 256 + kloc_ + k0;   \
      rB[2 * cc]     = *(const f32x4*)pb_;                                    \
      rB[2 * cc + 1] = *(const f32x4*)(pb_ + 4);                              \
    }                                                                         \
  } while (0)

#define COMMIT_TILE(kk, dst) do {                                             \
    const uint neg_ = (0x284Eu >> ((a_idx << 2) | ((kk) >> 8))) & 1u;         \
    _Pragma("unroll")                                                         \
    for (int cc = 0; cc < 4; ++cc) {                                          \
      u32x4 va_;                                                              \
      va_[0] = pk2(rA[2 * cc][0], rA[2 * cc][1]);                             \
      va_[1] = pk2(rA[2 * cc][2], rA[2 * cc][3]);                             \
      va_[2] = pk2(rA[2 * cc + 1][0], rA[2 * cc + 1][1]);                     \
      va_[3] = pk2(rA[2 * cc + 1][2], rA[2 * cc + 1][3]);                     \
      *(u32x4*)((dst) + sbase + 4096 * cc) = va_;                             \
    }                                                                         \
    if (neg_) {                                                               \
      _Pragma("unroll")                                                       \
      for (int cc = 0; cc < 4; ++cc) {                                        \
        u32x4 vb_;                                                            \
        vb_[0] = pk2(-rB[2 * cc][0], -rB[2 * cc][1]);                         \
        vb_[1] = pk2(-rB[2 * cc][2], -rB[2 * cc][3]);                         \
        vb_[2] = pk2(-rB[2 * cc + 1][0], -rB[2 * cc + 1][1]);                 \
        vb_[3] = pk2(-rB[2 * cc + 1][2], -rB[2 * cc + 1][3]);                 \
        *(u32x4*)((dst) + 16384 + sbase + 4096 * cc) = vb_;                   \
      }                                                                       \
    } else {                                                                  \
      _Pragma("unroll")                                                       \
      for (int cc = 0; cc < 4; ++cc) {                                        \
        u32x4 vb_;                                                            \
        vb_[0] = pk2(rB[2 * cc][0], rB[2 * cc][1]);                           \
        vb_[1] = pk2(rB[2 * cc][2], rB[2 * cc][3]);                           \
        vb_[2] = pk2(rB[2 * cc + 1][0], rB[2 * cc + 1][1]);                   \
        vb_[3] = pk2(rB[2 * cc + 1][2], rB[2 * cc + 1][3]);                   \
        *(u32x4*)((dst) + 16384 + sbase + 4096 * cc) = vb_;                   \
      }                                                                       \
    }                                                                         \
  } while (0)

#define COMPUTE_TILE(src) do {                                                \
    _Pragma("unroll")                                                         \
    for (int ks = 0; ks < 2; ++ks) {                                          \
      const int kb_ = (ks << 6) + fkb;                                        \
      bf16x8 af_[4], bf_[4];                                                  \
      _Pragma("unroll")                                                       \
      for (int mi = 0; mi < 4; ++mi) {                                        \
        const int row_ = frow_a0 + (mi << 4);                                 \
        af_[mi] = *(const bf16x8*)((src) + row_ * (BK * 2)                    \
                                   + (kb_ ^ ((row_ & 7) << 4)));              \
      }                                                                       \
      _Pragma("unroll")                                                       \
      for (int ni = 0; ni < 4; ++ni) {                                        \
        const int row_ = frow_b0 + (ni << 4);                                 \
        bf_[ni] = *(const bf16x8*)((src) + 16384 + row_ * (BK * 2)            \
                                   + (kb_ ^ ((row_ & 7) << 4)));              \
      }                                                                       \
      _Pragma("unroll")                                                       \
      for (int mi = 0; mi < 4; ++mi)                                          \
        _Pragma("unroll")                                                     \
        for (int ni = 0; ni < 4; ++ni)                                        \
          acc[mi][ni] = __builtin_amdgcn_mfma_f32_16x16x32_bf16(              \
              af_[mi], bf_[ni], acc[mi][ni], 0, 0, 0);                        \
    }                                                                         \
  } while (0)

__global__ __launch_bounds__(NTHREADS, 2) void qlin_gemm(
    const float* __restrict__ X, const float* __restrict__ Rm,
    const float* __restrict__ Im, const float* __restrict__ Jm,
    const float* __restrict__ Km, const float* __restrict__ bias,
    float* __restrict__ Y)
{
  const int per = ((M_TOTAL / BM) * (N_TOTAL / BN)) >> 3;
  const int bid = (int)blockIdx.x;
  const int swz = (bid & 7) * per + (bid >> 3);
  const int m0 = (swz >> 3) * BM;
  const int n0 = (swz & 7) * BN;

  const int tid = (int)threadIdx.x;
  const int lane = tid & 63;
  const int wave = tid >> 6;
  const int wm = (wave >> 1) << 6;
  const int wn = (wave & 1) << 6;

  __shared__ __align__(16) ushort sm[2 * 2 * BM * BK];
  char* const cS = (char*)sm;

  const int a_idx = n0 >> 8;
  const int o_src = n0 & 255;

  const int r0 = tid >> 3;
  const int k0 = (tid & 7) << 3;
  const int sbase = r0 * (BK * 2) + ((k0 * 2) ^ ((r0 & 7) << 4));

  f32x4 rA[8], rB[8];
  f32x4 acc[4][4];
#pragma unroll
  for (int i = 0; i < 4; ++i)
#pragma unroll
    for (int j = 0; j < 4; ++j) acc[i][j] = (f32x4)(0.0f);

  const int frow_a0 = wm + (lane & 15);
  const int frow_b0 = wn + (lane & 15);
  const int fkb = (lane >> 4) << 4;

  LOAD_TILE(0);
  COMMIT_TILE(0, cS);
  LOAD_TILE(BK);
  SOFT_BARRIER();

#pragma unroll 1
  for (int k = 0; k < NSTEPS; ++k) {
    char* const rbuf = cS + ((k & 1) << 15);
    char* const wbuf = cS + (((k + 1) & 1) << 15);
    if (k + 1 < NSTEPS) COMMIT_TILE((k + 1) * BK, wbuf);
    if (k + 2 < NSTEPS) LOAD_TILE((k + 2) * BK);
    COMPUTE_TILE(rbuf);
    SOFT_BARRIER();
  }

#pragma unroll
  for (int ni = 0; ni < 4; ++ni) {
    const int col = n0 + wn + (ni << 4) + (lane & 15);
    const float bv = bias[col];
#pragma unroll
    for (int mi = 0; mi < 4; ++mi) {
      const int r0e = m0 + wm + (mi << 4) + ((lane >> 4) << 2);
#pragma unroll
      for (int j = 0; j < 4; ++j)
        Y[(size_t)(r0e + j) * N_TOTAL + col] = acc[mi][ni][j] + bv;
    }
  }
}

extern "C" void kernel_launch(void* const* d_in, const int* in_sizes, int n_in,
                              void* d_out, int out_size, void* d_ws, size_t ws_size,
                              hipStream_t stream) {
  const float* X = (const float*)d_in[0];
  const float* Rm = (const float*)d_in[1];
  const float* Im = (const float*)d_in[2];
  const float* Jm = (const float*)d_in[3];
  const float* Km = (const float*)d_in[4];
  const float* bias = (const float*)d_in[5];
  float* Y = (float*)d_out;

  const size_t needB = (size_t)4 * 256 * 256 * 2;            // 512 KB
  const size_t needX = (size_t)M_TOTAL * K_TOTAL * 2;        // 64 MB

  if (ws_size >= needX + needB) {
    ushort* wsx = (ushort*)d_ws;
    ushort* wsb = wsx + (size_t)M_TOTAL * K_TOTAL;
    conv_xb<<<dim3(16384 + 128), dim3(256), 0, stream>>>(X, Rm, Im, Jm, Km, wsx);
    qlin_gemm9<<<dim3(2048), dim3(256), 0, stream>>>(wsx, wsb, bias, Y);
  } else if (ws_size >= needB) {
    ushort* wsb = (ushort*)d_ws;
    conv_b<<<dim3(128), dim3(256), 0, stream>>>(Rm, Im, Jm, Km, wsb);
    qlin_gemm2<<<dim3((M_TOTAL / BM2) * (N_TOTAL / BN2)), dim3(NT2), 0, stream>>>(
        X, wsb, bias, Y);
  } else {
    qlin_gemm<<<dim3((M_TOTAL / BM) * (N_TOTAL / BN)), dim3(NTHREADS), 0, stream>>>(
        X, Rm, Im, Jm, Km, bias, Y);
  }
}